// Round 13
// baseline (81.842 us; speedup 1.0000x reference)
//
#include <hip/hip_runtime.h>
#include <hip/hip_bf16.h>

#define BS  32
#define J   4
#define L   512
#define D   768
#define K   4
#define OUT 256
// entity e = b*16 + j*4 + k (reference reshape order); sentence = e>>2 (128)
// Single dispatch, 1536 blocks x 256 threads:
//   blk <  1024 : pool role  — entity e = blk>>1, half h = blk&1 (R5 proven)
//   blk >= 1024 : gemm role  — tile t = blk-1024: sentence g = t>>2, cq = t&3
// Pool blocks of sentence g are blks [8g, 8g+8); each bumps cnt[g] with an
// agent-scope RELEASE add after its ws stores completed (syncthreads drains
// vmcnt). Gemm blocks ACQUIRE-spin until cnt[g]==8 (pattern proven in R10).
// Deadlock-free: 28KB LDS -> 5 blocks/CU -> 1280 slots > 512 max spinners.

typedef float f4 __attribute__((ext_vector_type(4)));

__global__ __launch_bounds__(256) void fused_kernel(
    const float* __restrict__ Z,    // [BS,J,L,D]
    const int*   __restrict__ sep,  // [BS,J,K]
    const float* __restrict__ W,    // [D, OUT]
    const float* __restrict__ bias, // [OUT]
    float*       __restrict__ out,  // [512, OUT]
    float*       __restrict__ ws,   // [128][2][4][768] scaled half-pools
    int*         __restrict__ cnt)  // [128] arrival counters (zeroed per call)
{
    __shared__ union {
        float part[4][D];                      // pool: 12 KB
        struct {
            float p[K * D];                    // gemm: 12 KB
            float red[16][K][64];              // gemm: 16 KB
        } bb;                                  // gemm: 28 KB
    } sm;

    const int blk = blockIdx.x;
    const int tid = threadIdx.x;

    if (blk < 1024) {
        // ================= pool role (R5 proven body) =======================
        const int e    = blk >> 1, h = blk & 1;
        const int sent = e >> 2,  k = e & 3;
        const int end   = sep[sent * K + k];
        const int prev  = (k == 0) ? 0 : sep[sent * K + k - 1];
        const int start = prev + 1;
        const float inv = 1.0f / (float)(end - start);

        const int w    = tid >> 6;
        const int lane = tid & 63;
        const float* zbase = Z + (size_t)sent * L * D + lane * 4;

        f4 a0={0,0,0,0}, a1={0,0,0,0}, a2={0,0,0,0};
        f4 c0={0,0,0,0}, c1={0,0,0,0}, c2={0,0,0,0};

        int l = start + h + 2 * w;             // this wave: stride 8
        for (; l + 8 < end; l += 16) {         // 2 tokens/iter: 6 loads in flight
            const float* r0 = zbase + (size_t)l * D;
            const float* r1 = zbase + (size_t)(l + 8) * D;
            a0 += *(const f4*)(r0);       a1 += *(const f4*)(r0 + 256);
            a2 += *(const f4*)(r0 + 512);
            c0 += *(const f4*)(r1);       c1 += *(const f4*)(r1 + 256);
            c2 += *(const f4*)(r1 + 512);
        }
        if (l < end) {
            const float* r0 = zbase + (size_t)l * D;
            a0 += *(const f4*)(r0);       a1 += *(const f4*)(r0 + 256);
            a2 += *(const f4*)(r0 + 512);
        }
        a0 += c0; a1 += c1; a2 += c2;

        *(f4*)&sm.part[w][lane*4]       = a0;
        *(f4*)&sm.part[w][lane*4 + 256] = a1;
        *(f4*)&sm.part[w][lane*4 + 512] = a2;
        __syncthreads();

        if (tid < 192) {                       // 192 f4 = 768 floats
            f4 s = {0,0,0,0};
            #pragma unroll
            for (int ww = 0; ww < 4; ++ww) s += *(const f4*)&sm.part[ww][tid*4];
            s *= inv;                          // pre-scale by 1/count
            *(f4*)&ws[(((size_t)sent*2 + h)*K + k) * D + tid*4] = s;
        }
        __syncthreads();                       // drains vmcnt: ws stores complete
        if (tid == 0)
            __hip_atomic_fetch_add(&cnt[sent], 1, __ATOMIC_RELEASE,
                                   __HIP_MEMORY_SCOPE_AGENT);
        return;
    }

    // ================= gemm role (R5 proven body) ===========================
    const int t  = blk - 1024;
    const int g  = t >> 2;                     // sentence
    const int cq = t & 3;                      // col quarter

    if (tid == 0) {                            // acquire-spin until pools done
        while (__hip_atomic_load(&cnt[g], __ATOMIC_ACQUIRE,
                                 __HIP_MEMORY_SCOPE_AGENT) != 8)
            __builtin_amdgcn_s_sleep(8);
    }
    __syncthreads();

    {
        const f4* a = (const f4*)(ws + (size_t)g * 2 * K * D);
        #pragma unroll
        for (int i = tid; i < (K * D) / 4; i += 256)
            *(f4*)&sm.bb.p[i * 4] = a[i] + a[i + (K * D) / 4];
    }
    __syncthreads();

    const int w    = tid >> 6;
    const int lane = tid & 63;
    const int dg   = lane >> 4;
    const int cl   = lane & 15;
    const int colbase = cq * 64 + cl * 4;
    const int dbase   = w * 192 + dg;

    f4 acc0={0,0,0,0}, acc1={0,0,0,0}, acc2={0,0,0,0}, acc3={0,0,0,0};
    #pragma unroll 4
    for (int i = 0; i < 48; ++i) {
        const int d = dbase + 4 * i;
        f4 wv = *(const f4*)&W[(size_t)d * OUT + colbase];   // 16B coalesced
        acc0 += sm.bb.p[0 * D + d] * wv;       // LDS broadcast within dg group
        acc1 += sm.bb.p[1 * D + d] * wv;
        acc2 += sm.bb.p[2 * D + d] * wv;
        acc3 += sm.bb.p[3 * D + d] * wv;
    }

    const int r = w * 4 + dg;
    *(f4*)&sm.bb.red[r][0][cl * 4] = acc0;
    *(f4*)&sm.bb.red[r][1][cl * 4] = acc1;
    *(f4*)&sm.bb.red[r][2][cl * 4] = acc2;
    *(f4*)&sm.bb.red[r][3][cl * 4] = acc3;
    __syncthreads();

    const int e2  = tid >> 6;                  // entity
    const int col = tid & 63;                  // col within quarter
    float s = bias[cq * 64 + col];
    #pragma unroll
    for (int rr = 0; rr < 16; ++rr) s += sm.bb.red[rr][e2][col];
    out[(size_t)(g * K + e2) * OUT + cq * 64 + col] = s;
}

extern "C" void kernel_launch(void* const* d_in, const int* in_sizes, int n_in,
                              void* d_out, int out_size, void* d_ws, size_t ws_size,
                              hipStream_t stream) {
    const float* Z    = (const float*)d_in[0];
    const int*   sep  = (const int*)d_in[1];
    const float* W    = (const float*)d_in[2];
    const float* bias = (const float*)d_in[3];
    float*       out  = (float*)d_out;
    float*       ws   = (float*)d_ws;                    // 3 MB half-pools
    int*         cnt  = (int*)(ws + (size_t)128 * 2 * K * D); // +512 B counters

    hipMemsetAsync(cnt, 0, 128 * sizeof(int), stream);   // graph-legal node
    fused_kernel<<<1536, 256, 0, stream>>>(Z, sep, W, bias, out, ws, cnt);
}